// Round 2
// baseline (29.109 us; speedup 1.0000x reference)
//
#include <hip/hip_runtime.h>

typedef unsigned int u32;
typedef unsigned long long u64;

#define NEXP   64
#define TPB    256
#define EPB    4096            // elements per block
#define WPB    4               // waves per block
#define CHUNK  1024            // elements per wave
#define ROUNDS 16              // 64-element rounds per wave

// ---------------- K1: per-block (4096-elem) histogram ----------------
// sshist[b][e], b = 0..nb-1
__global__ __launch_bounds__(TPB) void k_hist(const int* __restrict__ experts,
                                              u32* __restrict__ sshist) {
    __shared__ u32 h[NEXP];
    const int t = threadIdx.x;
    if (t < NEXP) h[t] = 0;
    __syncthreads();
    // 4096 elems / 256 thr = 16 per thread = 4x int4, coalesced
    const int4* p = (const int4*)(experts + (size_t)blockIdx.x * EPB);
#pragma unroll
    for (int r = 0; r < 4; ++r) {
        int4 v = p[r * TPB + t];
        atomicAdd(&h[v.x], 1u);
        atomicAdd(&h[v.y], 1u);
        atomicAdd(&h[v.z], 1u);
        atomicAdd(&h[v.w], 1u);
    }
    __syncthreads();
    if (t < NEXP) sshist[(size_t)blockIdx.x * NEXP + t] = h[t];
}

// ---------------- K2: fused scan + stable scatter ----------------
__global__ __launch_bounds__(TPB) void k_scatter(const float* __restrict__ scores,
                                                 const int* __restrict__ experts,
                                                 const u32* __restrict__ sshist,
                                                 float* __restrict__ out_scores,
                                                 float* __restrict__ out_idx,
                                                 float* __restrict__ out_counts,
                                                 int nb) {
    __shared__ u32 Ppart[WPB][NEXP], Tpart[WPB][NEXP];
    __shared__ u32 P[NEXP], Tt[NEXP], base[NEXP];
    __shared__ u32 h[WPB][NEXP];
    __shared__ u32 cnt[WPB][NEXP];

    const int t    = threadIdx.x;
    const int lane = t & 63;
    const int s    = t >> 6;      // wave id == stripe id == chunk-in-block id
    const int b    = blockIdx.x;

    // ---- Phase A: global prefix over superblocks + expert totals ----
    u32 plt = 0, pall = 0;
    const int stripe = nb / WPB;  // 64 superblocks per stripe
    for (int k = 0; k < stripe; ++k) {
        const int bp = s * stripe + k;
        const u32 v = sshist[(size_t)bp * NEXP + lane];
        pall += v;
        if (bp < b) plt += v;
    }
    Ppart[s][lane] = plt;
    Tpart[s][lane] = pall;
    h[s][lane] = 0;               // zero per-chunk hists while we're here
    __syncthreads();

    if (t < NEXP) {
        const u32 p  = Ppart[0][t] + Ppart[1][t] + Ppart[2][t] + Ppart[3][t];
        const u32 tt = Tpart[0][t] + Tpart[1][t] + Tpart[2][t] + Tpart[3][t];
        P[t]  = p;
        Tt[t] = tt;
        // exclusive scan over experts (single wave: t == lane)
        u32 x = tt;
#pragma unroll
        for (int d = 1; d < 64; d <<= 1) {
            u32 y = __shfl_up(x, d);
            if (lane >= d) x += y;
        }
        base[t] = x - tt;
    }
    __syncthreads();

    // ---- Phase B: per-chunk hist from register-cached experts ----
    const int wbase = b * EPB + s * CHUNK;   // wave's first element index
    int e[ROUNDS];
#pragma unroll
    for (int r = 0; r < ROUNDS; ++r) {
        e[r] = experts[wbase + r * 64 + lane];
        atomicAdd(&h[s][e[r]], 1u);
    }
    __syncthreads();

    // seed per-wave running counters: global base + superblock prefix +
    // in-block chunk prefix
    u32 cseed = base[lane] + P[lane];
    for (int j = 0; j < s; ++j) cseed += h[j][lane];
    cnt[s][lane] = cseed;         // wave-private from here on

    if (b == 0 && t < NEXP) out_counts[t] = (float)Tt[t];

    // ---- Phase C: barrier-free stable scatter ----
#pragma unroll
    for (int r = 0; r < ROUNDS; ++r) {
        const int i = wbase + r * 64 + lane;
        const float sc = scores[i];
        const int ee = e[r];
        // match-any over the 6-bit expert id
        u64 m = ~0ull;
#pragma unroll
        for (int bb = 0; bb < 6; ++bb) {
            const u64 bl = __ballot((ee >> bb) & 1);
            m &= ((ee >> bb) & 1) ? bl : ~bl;
        }
        const u64 below = m & ((1ull << lane) - 1ull);
        const u32 lower = (u32)__popcll(below);
        const u32 pos = cnt[s][ee] + lower;
        out_scores[pos] = sc;
        out_idx[pos]    = (float)(i >> 3);    // original index / TOP_K
        if (lower == 0) cnt[s][ee] += (u32)__popcll(m);   // leader update
    }
}

extern "C" void kernel_launch(void* const* d_in, const int* in_sizes, int n_in,
                              void* d_out, int out_size, void* d_ws, size_t ws_size,
                              hipStream_t stream) {
    const float* top_scores = (const float*)d_in[0];
    const int*   experts    = (const int*)d_in[1];

    const int M  = in_sizes[0];      // 1,048,576
    const int nb = M / EPB;          // 256

    u32* sshist = (u32*)d_ws;        // nb * 64 u32 = 64 KB

    float* out        = (float*)d_out;
    float* out_scores = out;                     // M
    float* out_idx    = out + M;                 // M
    float* out_counts = out + 2 * (size_t)M;     // 64

    k_hist<<<nb, TPB, 0, stream>>>(experts, sshist);
    k_scatter<<<nb, TPB, 0, stream>>>(top_scores, experts, sshist,
                                      out_scores, out_idx, out_counts, nb);
}

// Round 3
// 20.393 us; speedup vs baseline: 1.4274x; 1.4274x over previous
//
#include <hip/hip_runtime.h>

typedef unsigned int u32;
typedef unsigned long long u64;
typedef unsigned char u8;

#define NEXP   64
#define TPB    256
#define EPB    4096            // elements per block
#define WPB    4               // waves per block
#define CHUNK  1024            // elements per wave
#define ROUNDS 16              // 64-elem rounds per wave

// ---------------- K1: per-block histogram ----------------
__global__ __launch_bounds__(TPB) void k_hist(const int* __restrict__ experts,
                                              u32* __restrict__ sshist) {
    __shared__ u32 h[NEXP];
    const int t = threadIdx.x;
    if (t < NEXP) h[t] = 0;
    __syncthreads();
    const int4* p = (const int4*)(experts + (size_t)blockIdx.x * EPB);
#pragma unroll
    for (int r = 0; r < 4; ++r) {
        int4 v = p[r * TPB + t];
        atomicAdd(&h[v.x], 1u);
        atomicAdd(&h[v.y], 1u);
        atomicAdd(&h[v.z], 1u);
        atomicAdd(&h[v.w], 1u);
    }
    __syncthreads();
    if (t < NEXP) sshist[(size_t)blockIdx.x * NEXP + t] = h[t];
}

// ---------------- K2: per-expert exclusive scan across blocks ----------
// grid = NEXP blocks (one expert each), block = nb threads (256)
__global__ __launch_bounds__(TPB) void k_scan(u32* __restrict__ sshist,
                                              u32* __restrict__ totals,
                                              float* __restrict__ out_counts,
                                              int nb) {
    const int e = blockIdx.x;
    const int t = threadIdx.x;          // block id
    const int lane = t & 63, wv = t >> 6;
    const u32 v = sshist[(size_t)t * NEXP + e];
    u32 x = v;
#pragma unroll
    for (int d = 1; d < 64; d <<= 1) {
        u32 y = __shfl_up(x, d);
        if (lane >= d) x += y;
    }
    __shared__ u32 ws[WPB];
    if (lane == 63) ws[wv] = x;
    __syncthreads();
    u32 add = 0;
    for (int j = 0; j < wv; ++j) add += ws[j];
    const u32 incl = add + x;
    sshist[(size_t)t * NEXP + e] = incl - v;     // exclusive prefix (in place)
    if (t == nb - 1) {
        totals[e] = incl;
        out_counts[e] = (float)incl;
    }
}

// ---------------- K3: local stable sort in LDS + coalesced write-out ----
__global__ __launch_bounds__(TPB) void k_scatter(const float* __restrict__ scores,
                                                 const int* __restrict__ experts,
                                                 const u32* __restrict__ pre,
                                                 const u32* __restrict__ totals,
                                                 float* __restrict__ out_scores,
                                                 float* __restrict__ out_idx) {
    __shared__ u32 gdst[NEXP];      // base[e] + pre[b][e]
    __shared__ u32 lexcl[NEXP];     // in-block exclusive prefix by expert
    __shared__ u32 h[WPB][NEXP];    // per-wave-chunk hist
    __shared__ u32 cnt[WPB][NEXP];  // running local slot counters (wave-private)
    __shared__ float ssc[EPB];
    __shared__ u32   sidx[EPB];
    __shared__ u8    eid[EPB];

    const int t    = threadIdx.x;
    const int lane = t & 63;
    const int s    = t >> 6;
    const int b    = blockIdx.x;

    // issue small global loads early (wave 0 only)
    u32 pr = 0, tot = 0;
    if (s == 0) {
        pr  = pre[(size_t)b * NEXP + lane];
        tot = totals[lane];
    }

    h[s][lane] = 0;
    __syncthreads();

    // per-wave hist from register-cached experts
    const int wbase = b * EPB + s * CHUNK;
    int e[ROUNDS];
#pragma unroll
    for (int r = 0; r < ROUNDS; ++r) {
        e[r] = experts[wbase + r * 64 + lane];
        atomicAdd(&h[s][e[r]], 1u);
    }

    // wave 0: expert base offsets (scan of totals) + global dst for this block
    if (s == 0) {
        u32 x = tot;
#pragma unroll
        for (int d = 1; d < 64; d <<= 1) {
            u32 y = __shfl_up(x, d);
            if (lane >= d) x += y;
        }
        gdst[lane] = (x - tot) + pr;
    }
    __syncthreads();

    // in-block expert prefix + per-wave counter seeds (thread t == expert t)
    if (t < NEXP) {
        const u32 h0 = h[0][t], h1 = h[1][t], h2 = h[2][t], h3 = h[3][t];
        const u32 H = h0 + h1 + h2 + h3;
        u32 x = H;
#pragma unroll
        for (int d = 1; d < 64; d <<= 1) {
            u32 y = __shfl_up(x, d);
            if (t >= d) x += y;
        }
        const u32 lex = x - H;
        lexcl[t]  = lex;
        cnt[0][t] = lex;
        cnt[1][t] = lex + h0;
        cnt[2][t] = lex + h0 + h1;
        cnt[3][t] = lex + h0 + h1 + h2;
    }
    __syncthreads();

    // stable scatter into LDS (barrier-free: cnt rows are wave-private)
#pragma unroll
    for (int r = 0; r < ROUNDS; ++r) {
        const int i = wbase + r * 64 + lane;
        const float sc = scores[i];
        const int ee = e[r];
        u64 m = ~0ull;
#pragma unroll
        for (int bb = 0; bb < 6; ++bb) {
            const u64 bl = __ballot((ee >> bb) & 1);
            m &= ((ee >> bb) & 1) ? bl : ~bl;
        }
        const u64 below = m & ((1ull << lane) - 1ull);
        const u32 lower = (u32)__popcll(below);
        const u32 slot = cnt[s][ee] + lower;
        ssc[slot]  = sc;
        sidx[slot] = (u32)(i >> 3);     // original index / TOP_K
        eid[slot]  = (u8)ee;
        if (lower == 0) cnt[s][ee] += (u32)__popcll(m);
    }
    __syncthreads();

    // coalesced write-out in block-sorted order
#pragma unroll
    for (int r = 0; r < ROUNDS; ++r) {
        const int j = r * TPB + t;
        const u32 ee = eid[j];
        const u32 dst = gdst[ee] + (u32)j - lexcl[ee];
        out_scores[dst] = ssc[j];
        out_idx[dst]    = (float)sidx[j];
    }
}

extern "C" void kernel_launch(void* const* d_in, const int* in_sizes, int n_in,
                              void* d_out, int out_size, void* d_ws, size_t ws_size,
                              hipStream_t stream) {
    const float* top_scores = (const float*)d_in[0];
    const int*   experts    = (const int*)d_in[1];

    const int M  = in_sizes[0];      // 1,048,576
    const int nb = M / EPB;          // 256

    u32* sshist = (u32*)d_ws;                     // nb*64 u32 (scanned in place)
    u32* totals = sshist + (size_t)nb * NEXP;     // 64 u32

    float* out        = (float*)d_out;
    float* out_scores = out;                      // M
    float* out_idx    = out + M;                  // M
    float* out_counts = out + 2 * (size_t)M;      // 64

    k_hist<<<nb, TPB, 0, stream>>>(experts, sshist);
    k_scan<<<NEXP, nb, 0, stream>>>(sshist, totals, out_counts, nb);
    k_scatter<<<nb, TPB, 0, stream>>>(top_scores, experts, sshist, totals,
                                      out_scores, out_idx);
}